// Round 1
// baseline (342.795 us; speedup 1.0000x reference)
//
#include <hip/hip_runtime.h>

#define BATCH 256
#define NP 64
#define DIM 512
#define NH 8
#define SCALE 0.125f
#define THREADS 512

// LDS layout (floats):
//   big  [0, 32768)   : phase A scratch union / ks / W2 [64][512] / t-partials
//   wl   [32768,36864): staged Wspec panel (k-part, then q-part transposed)
//   s_l  [36864,37376): spatial_out row s[512]
#define LDS_FLOATS (32768 + 4096 + 512)
#define LDS_BYTES (LDS_FLOATS * 4)

__global__ __launch_bounds__(THREADS, 1)
void center_attn_kernel(const float* __restrict__ x,
                        const float* __restrict__ Wq,
                        const float* __restrict__ Wkv,
                        const float* __restrict__ Wout,
                        const float* __restrict__ bout,
                        const float* __restrict__ Wspec,
                        float* __restrict__ out) {
  extern __shared__ float lds[];
  float* big = lds;
  float* wl  = lds + 32768;
  float* s_l = lds + 32768 + 4096;

  const int t = threadIdx.x;
  const int lane = t & 63;
  const int wave = t >> 6;
  const int b = blockIdx.x;
  const float* xb = x + (size_t)b * NP * DIM;

  // phase-A scratch inside big
  float* x32 = big;          // 512
  float* qc  = big + 512;    // 512
  float* u   = big + 1024;   // 8*512
  float* pT  = big + 5120;   // 64*8   (p transposed: [m][h])
  float* y   = big + 5632;   // 8*512
  float* o   = big + 9728;   // 512

  // P0: stage center row
  x32[t] = xb[32 * DIM + t];
  __syncthreads();

  // P1: qc[j] = sum_d x32[d] * Wq[d][j]
  {
    float acc = 0.f;
    #pragma unroll 8
    for (int d = 0; d < DIM; ++d)
      acc = fmaf(x32[d], Wq[(size_t)d * DIM + t], acc);
    qc[t] = acc;
  }
  __syncthreads();

  // P2: u[h][d] = sum_jj Wkv[d][h*64+jj] * qc[h*64+jj], d = t
  {
    const float4* wk4 = reinterpret_cast<const float4*>(Wkv + (size_t)t * 1024);
    #pragma unroll
    for (int h = 0; h < NH; ++h) {
      const float4* q4 = reinterpret_cast<const float4*>(qc + h * 64);
      float acc = 0.f;
      #pragma unroll
      for (int jj = 0; jj < 16; ++jj) {
        float4 wv = wk4[h * 16 + jj];
        float4 qv = q4[jj];
        acc = fmaf(wv.x, qv.x, acc);
        acc = fmaf(wv.y, qv.y, acc);
        acc = fmaf(wv.z, qv.z, acc);
        acc = fmaf(wv.w, qv.w, acc);
      }
      u[h * DIM + t] = acc;
    }
  }
  __syncthreads();

  // P3: scores + per-head softmax. wave = head h, lane = key index m
  {
    const int h = wave, m = lane;
    const float4* xr = reinterpret_cast<const float4*>(xb + (size_t)m * DIM);
    const float4* ur = reinterpret_cast<const float4*>(u + h * DIM);
    float acc = 0.f;
    #pragma unroll 8
    for (int i = 0; i < DIM / 4; ++i) {
      float4 xv = xr[i], uv = ur[i];
      acc = fmaf(xv.x, uv.x, acc);
      acc = fmaf(xv.y, uv.y, acc);
      acc = fmaf(xv.z, uv.z, acc);
      acc = fmaf(xv.w, uv.w, acc);
    }
    float sc = acc * SCALE;
    float mx = sc;
    #pragma unroll
    for (int off = 32; off > 0; off >>= 1)
      mx = fmaxf(mx, __shfl_xor(mx, off));
    float ev = __expf(sc - mx);
    float sm = ev;
    #pragma unroll
    for (int off = 32; off > 0; off >>= 1)
      sm += __shfl_xor(sm, off);
    pT[m * NH + h] = ev / sm;
  }
  __syncthreads();

  // P4: y[h][d] = sum_m p[h][m] * x[m][d], d = t
  {
    float acc[NH];
    #pragma unroll
    for (int h = 0; h < NH; ++h) acc[h] = 0.f;
    for (int m = 0; m < NP; ++m) {
      float xv = xb[(size_t)m * DIM + t];
      const float4* pp = reinterpret_cast<const float4*>(pT + m * NH);
      float4 p0 = pp[0], p1 = pp[1];
      acc[0] = fmaf(p0.x, xv, acc[0]);
      acc[1] = fmaf(p0.y, xv, acc[1]);
      acc[2] = fmaf(p0.z, xv, acc[2]);
      acc[3] = fmaf(p0.w, xv, acc[3]);
      acc[4] = fmaf(p1.x, xv, acc[4]);
      acc[5] = fmaf(p1.y, xv, acc[5]);
      acc[6] = fmaf(p1.z, xv, acc[6]);
      acc[7] = fmaf(p1.w, xv, acc[7]);
    }
    #pragma unroll
    for (int h = 0; h < NH; ++h) y[h * DIM + t] = acc[h];
  }
  __syncthreads();

  // P5: o[j] = sum_d y[h][d] * Wkv[d][512+j], j = t, h = wave
  {
    const float* yr = y + wave * DIM;
    float acc = 0.f;
    #pragma unroll 8
    for (int d = 0; d < DIM; ++d)
      acc = fmaf(yr[d], Wkv[(size_t)d * 1024 + 512 + t], acc);
    o[t] = acc;
  }
  __syncthreads();

  // P6: s[e] = bout[e] + sum_j o[j] * Wout[j][e], e = t
  {
    float acc = bout[t];
    #pragma unroll 8
    for (int j = 0; j < DIM; ++j)
      acc = fmaf(o[j], Wout[(size_t)j * DIM + t], acc);
    s_l[t] = acc;
  }
  __syncthreads();

  // P7a: stage Wspec k-part (scaled): wl[m][n] = Wspec[m][64+n] * SCALE
  for (int i = t; i < 4096; i += THREADS) {
    int m = i >> 6, n = i & 63;
    wl[i] = Wspec[m * 192 + 64 + n] * SCALE;
  }
  __syncthreads();

  // P7b: ks[n][e] = sum_m x[m][e] * wl[m][n], e = t  (overwrites big)
  {
    float acc[64];
    #pragma unroll
    for (int n = 0; n < 64; ++n) acc[n] = 0.f;
    for (int m = 0; m < NP; ++m) {
      float xv = xb[(size_t)m * DIM + t];
      const float4* w4 = reinterpret_cast<const float4*>(wl + m * 64);
      #pragma unroll
      for (int n4 = 0; n4 < 16; ++n4) {
        float4 wv = w4[n4];
        acc[n4 * 4 + 0] = fmaf(xv, wv.x, acc[n4 * 4 + 0]);
        acc[n4 * 4 + 1] = fmaf(xv, wv.y, acc[n4 * 4 + 1]);
        acc[n4 * 4 + 2] = fmaf(xv, wv.z, acc[n4 * 4 + 2]);
        acc[n4 * 4 + 3] = fmaf(xv, wv.w, acc[n4 * 4 + 3]);
      }
    }
    #pragma unroll
    for (int n = 0; n < 64; ++n) big[n * DIM + t] = acc[n];
  }
  __syncthreads();

  // P8a: stage Wspec q-part transposed: wl[n][m] = Wspec[m][n]
  for (int i = t; i < 4096; i += THREADS) {
    int n = i >> 6, m = i & 63;
    wl[i] = Wspec[m * 192 + n];
  }
  __syncthreads();

  // P8b: W2[m][e] = sum_n wq[m][n] * ks[n][e]; overwrite own column e = t
  {
    float acc[64];
    #pragma unroll
    for (int m = 0; m < 64; ++m) acc[m] = 0.f;
    for (int n = 0; n < NP; ++n) {
      float ksv = big[n * DIM + t];
      const float4* w4 = reinterpret_cast<const float4*>(wl + n * 64);
      #pragma unroll
      for (int m4 = 0; m4 < 16; ++m4) {
        float4 wv = w4[m4];
        acc[m4 * 4 + 0] = fmaf(ksv, wv.x, acc[m4 * 4 + 0]);
        acc[m4 * 4 + 1] = fmaf(ksv, wv.y, acc[m4 * 4 + 1]);
        acc[m4 * 4 + 2] = fmaf(ksv, wv.z, acc[m4 * 4 + 2]);
        acc[m4 * 4 + 3] = fmaf(ksv, wv.w, acc[m4 * 4 + 3]);
      }
    }
    #pragma unroll
    for (int m = 0; m < 64; ++m) big[m * DIM + t] = acc[m];
  }
  __syncthreads();

  // Phase C: z rows, softmax, t accumulation.
  // z[d][e] = sum_m x[m][d] * W2[m][e]  (SCALE already folded)
  // wave handles rows d0..d0+7 per iter; lane covers e = lane*8..lane*8+7
  {
    float treg[8];
    #pragma unroll
    for (int j = 0; j < 8; ++j) treg[j] = 0.f;

    for (int iter = 0; iter < 8; ++iter) {
      const int d0 = iter * 64 + wave * 8;
      float acc[8][8];
      #pragma unroll
      for (int r = 0; r < 8; ++r)
        #pragma unroll
        for (int j = 0; j < 8; ++j) acc[r][j] = 0.f;

      #pragma unroll 4
      for (int m = 0; m < NP; ++m) {
        const float* xrow = xb + (size_t)m * DIM + d0;
        float4 xa = *reinterpret_cast<const float4*>(xrow);
        float4 xc = *reinterpret_cast<const float4*>(xrow + 4);
        const float* w2row = big + m * DIM + lane * 8;
        float4 k0 = *reinterpret_cast<const float4*>(w2row);
        float4 k1 = *reinterpret_cast<const float4*>(w2row + 4);
        float xq[8] = {xa.x, xa.y, xa.z, xa.w, xc.x, xc.y, xc.z, xc.w};
        #pragma unroll
        for (int r = 0; r < 8; ++r) {
          acc[r][0] = fmaf(xq[r], k0.x, acc[r][0]);
          acc[r][1] = fmaf(xq[r], k0.y, acc[r][1]);
          acc[r][2] = fmaf(xq[r], k0.z, acc[r][2]);
          acc[r][3] = fmaf(xq[r], k0.w, acc[r][3]);
          acc[r][4] = fmaf(xq[r], k1.x, acc[r][4]);
          acc[r][5] = fmaf(xq[r], k1.y, acc[r][5]);
          acc[r][6] = fmaf(xq[r], k1.z, acc[r][6]);
          acc[r][7] = fmaf(xq[r], k1.w, acc[r][7]);
        }
      }

      #pragma unroll
      for (int r = 0; r < 8; ++r) {
        float mx = acc[r][0];
        #pragma unroll
        for (int j = 1; j < 8; ++j) mx = fmaxf(mx, acc[r][j]);
        #pragma unroll
        for (int off = 32; off > 0; off >>= 1)
          mx = fmaxf(mx, __shfl_xor(mx, off));
        float pe[8];
        float sum = 0.f;
        #pragma unroll
        for (int j = 0; j < 8; ++j) {
          pe[j] = __expf(acc[r][j] - mx);
          sum += pe[j];
        }
        #pragma unroll
        for (int off = 32; off > 0; off >>= 1)
          sum += __shfl_xor(sum, off);
        float coef = s_l[d0 + r] / sum;
        #pragma unroll
        for (int j = 0; j < 8; ++j) treg[j] = fmaf(coef, pe[j], treg[j]);
      }
    }
    __syncthreads();  // all waves done reading W2 before reuse as partial buffer

    float4 t0 = {treg[0], treg[1], treg[2], treg[3]};
    float4 t1 = {treg[4], treg[5], treg[6], treg[7]};
    *reinterpret_cast<float4*>(big + wave * DIM + lane * 8) = t0;
    *reinterpret_cast<float4*>(big + wave * DIM + lane * 8 + 4) = t1;
    __syncthreads();

    float tf = 0.f;
    #pragma unroll
    for (int w = 0; w < 8; ++w) tf += big[w * DIM + t];

    float* ob = out + (size_t)b * NP * DIM + t;
    #pragma unroll 4
    for (int n = 0; n < NP; ++n) ob[n * DIM] = tf;
  }
}

extern "C" void kernel_launch(void* const* d_in, const int* in_sizes, int n_in,
                              void* d_out, int out_size, void* d_ws, size_t ws_size,
                              hipStream_t stream) {
  (void)in_sizes; (void)n_in; (void)out_size; (void)d_ws; (void)ws_size;
  const float* x     = (const float*)d_in[0];
  const float* Wq    = (const float*)d_in[1];
  const float* Wkv   = (const float*)d_in[2];
  const float* Wout  = (const float*)d_in[3];
  const float* bout  = (const float*)d_in[4];
  const float* Wspec = (const float*)d_in[5];
  float* out = (float*)d_out;

  hipFuncSetAttribute(reinterpret_cast<const void*>(center_attn_kernel),
                      hipFuncAttributeMaxDynamicSharedMemorySize, LDS_BYTES);
  center_attn_kernel<<<dim3(BATCH), dim3(THREADS), LDS_BYTES, stream>>>(
      x, Wq, Wkv, Wout, bout, Wspec, out);
}

// Round 2
// 273.799 us; speedup vs baseline: 1.2520x; 1.2520x over previous
//
#include <hip/hip_runtime.h>

#define BATCH 256
#define NP 64
#define DIM 512
#define NH 8
#define SCALE 0.125f
#define THREADS 512

// LDS layout (floats):
//   big  [0, 32768)   : phase A scratch union / ks / W2 [64][512] / t-partials
//   wl   [32768,36864): staged Wspec panel (k-part, then q-part transposed)
//   s_l  [36864,37376): spatial_out row s[512]
#define LDS_FLOATS (32768 + 4096 + 512)
#define LDS_BYTES (LDS_FLOATS * 4)

__global__ __launch_bounds__(THREADS, 2)
void center_attn_kernel(const float* __restrict__ x,
                        const float* __restrict__ Wq,
                        const float* __restrict__ Wkv,
                        const float* __restrict__ Wout,
                        const float* __restrict__ bout,
                        const float* __restrict__ Wspec,
                        float* __restrict__ out) {
  extern __shared__ float lds[];
  float* big = lds;
  float* wl  = lds + 32768;
  float* s_l = lds + 32768 + 4096;

  const int t = threadIdx.x;
  const int lane = t & 63;
  const int wave = t >> 6;
  const int b = blockIdx.x;
  const float* xb = x + (size_t)b * NP * DIM;

  // phase-A scratch inside big
  float* x32 = big;          // 512
  float* qc  = big + 512;    // 512
  float* u   = big + 1024;   // 8*512
  float* pT  = big + 5120;   // 64*8   (p transposed: [m][h])
  float* y   = big + 5632;   // 8*512
  float* o   = big + 9728;   // 512

  // P0: stage center row
  x32[t] = xb[32 * DIM + t];
  __syncthreads();

  // P1: qc[j] = sum_d x32[d] * Wq[d][j], j = t   (4 independent acc chains)
  {
    float a0 = 0.f, a1 = 0.f, a2 = 0.f, a3 = 0.f;
    #pragma unroll 4
    for (int d = 0; d < DIM; d += 4) {
      a0 = fmaf(x32[d + 0], Wq[(size_t)(d + 0) * DIM + t], a0);
      a1 = fmaf(x32[d + 1], Wq[(size_t)(d + 1) * DIM + t], a1);
      a2 = fmaf(x32[d + 2], Wq[(size_t)(d + 2) * DIM + t], a2);
      a3 = fmaf(x32[d + 3], Wq[(size_t)(d + 3) * DIM + t], a3);
    }
    qc[t] = (a0 + a1) + (a2 + a3);
  }
  __syncthreads();

  // P2: u[h][d] = sum_jj Wkv[d][h*64+jj] * qc[h*64+jj], d = t
  {
    const float4* wk4 = reinterpret_cast<const float4*>(Wkv + (size_t)t * 1024);
    #pragma unroll
    for (int h = 0; h < NH; ++h) {
      const float4* q4 = reinterpret_cast<const float4*>(qc + h * 64);
      float acc0 = 0.f, acc1 = 0.f;
      #pragma unroll
      for (int jj = 0; jj < 8; ++jj) {
        float4 wv = wk4[h * 16 + jj];
        float4 qv = q4[jj];
        acc0 = fmaf(wv.x, qv.x, acc0);
        acc0 = fmaf(wv.y, qv.y, acc0);
        acc0 = fmaf(wv.z, qv.z, acc0);
        acc0 = fmaf(wv.w, qv.w, acc0);
      }
      #pragma unroll
      for (int jj = 8; jj < 16; ++jj) {
        float4 wv = wk4[h * 16 + jj];
        float4 qv = q4[jj];
        acc1 = fmaf(wv.x, qv.x, acc1);
        acc1 = fmaf(wv.y, qv.y, acc1);
        acc1 = fmaf(wv.z, qv.z, acc1);
        acc1 = fmaf(wv.w, qv.w, acc1);
      }
      u[h * DIM + t] = acc0 + acc1;
    }
  }
  __syncthreads();

  // P3: scores + per-head softmax. wave = head h, lane = key index m
  {
    const int h = wave, m = lane;
    const float4* xr = reinterpret_cast<const float4*>(xb + (size_t)m * DIM);
    const float4* ur = reinterpret_cast<const float4*>(u + h * DIM);
    float a0 = 0.f, a1 = 0.f;
    #pragma unroll 8
    for (int i = 0; i < DIM / 4; i += 2) {
      float4 xv = xr[i], uv = ur[i];
      a0 = fmaf(xv.x, uv.x, a0);
      a0 = fmaf(xv.y, uv.y, a0);
      a0 = fmaf(xv.z, uv.z, a0);
      a0 = fmaf(xv.w, uv.w, a0);
      float4 xw = xr[i + 1], uw = ur[i + 1];
      a1 = fmaf(xw.x, uw.x, a1);
      a1 = fmaf(xw.y, uw.y, a1);
      a1 = fmaf(xw.z, uw.z, a1);
      a1 = fmaf(xw.w, uw.w, a1);
    }
    float sc = (a0 + a1) * SCALE;
    float mx = sc;
    #pragma unroll
    for (int off = 32; off > 0; off >>= 1)
      mx = fmaxf(mx, __shfl_xor(mx, off));
    float ev = __expf(sc - mx);
    float sm = ev;
    #pragma unroll
    for (int off = 32; off > 0; off >>= 1)
      sm += __shfl_xor(sm, off);
    pT[m * NH + h] = ev / sm;
  }
  __syncthreads();

  // P4: y[h][d] = sum_m p[h][m] * x[m][d], d = t
  {
    float acc[NH];
    #pragma unroll
    for (int h = 0; h < NH; ++h) acc[h] = 0.f;
    #pragma unroll 2
    for (int m = 0; m < NP; ++m) {
      float xv = xb[(size_t)m * DIM + t];
      const float4* pp = reinterpret_cast<const float4*>(pT + m * NH);
      float4 p0 = pp[0], p1 = pp[1];
      acc[0] = fmaf(p0.x, xv, acc[0]);
      acc[1] = fmaf(p0.y, xv, acc[1]);
      acc[2] = fmaf(p0.z, xv, acc[2]);
      acc[3] = fmaf(p0.w, xv, acc[3]);
      acc[4] = fmaf(p1.x, xv, acc[4]);
      acc[5] = fmaf(p1.y, xv, acc[5]);
      acc[6] = fmaf(p1.z, xv, acc[6]);
      acc[7] = fmaf(p1.w, xv, acc[7]);
    }
    #pragma unroll
    for (int h = 0; h < NH; ++h) y[h * DIM + t] = acc[h];
  }
  __syncthreads();

  // P5: o[j] = sum_d y[h][d] * Wkv[d][512+j], j = t, h = wave
  {
    const float* yr = y + wave * DIM;
    float a0 = 0.f, a1 = 0.f, a2 = 0.f, a3 = 0.f;
    #pragma unroll 4
    for (int d = 0; d < DIM; d += 4) {
      a0 = fmaf(yr[d + 0], Wkv[(size_t)(d + 0) * 1024 + 512 + t], a0);
      a1 = fmaf(yr[d + 1], Wkv[(size_t)(d + 1) * 1024 + 512 + t], a1);
      a2 = fmaf(yr[d + 2], Wkv[(size_t)(d + 2) * 1024 + 512 + t], a2);
      a3 = fmaf(yr[d + 3], Wkv[(size_t)(d + 3) * 1024 + 512 + t], a3);
    }
    o[t] = (a0 + a1) + (a2 + a3);
  }
  __syncthreads();

  // P6: s[e] = bout[e] + sum_j o[j] * Wout[j][e], e = t
  {
    float a0 = bout[t], a1 = 0.f, a2 = 0.f, a3 = 0.f;
    #pragma unroll 4
    for (int j = 0; j < DIM; j += 4) {
      a0 = fmaf(o[j + 0], Wout[(size_t)(j + 0) * DIM + t], a0);
      a1 = fmaf(o[j + 1], Wout[(size_t)(j + 1) * DIM + t], a1);
      a2 = fmaf(o[j + 2], Wout[(size_t)(j + 2) * DIM + t], a2);
      a3 = fmaf(o[j + 3], Wout[(size_t)(j + 3) * DIM + t], a3);
    }
    s_l[t] = (a0 + a1) + (a2 + a3);
  }
  __syncthreads();

  // P7a: stage Wspec k-part (scaled): wl[m][n] = Wspec[m][64+n] * SCALE
  for (int i = t; i < 4096; i += THREADS) {
    int m = i >> 6, n = i & 63;
    wl[i] = Wspec[m * 192 + 64 + n] * SCALE;
  }
  __syncthreads();

  // P7b: ks[n][e] = sum_m x[m][e] * wl[m][n], e = t  (overwrites big)
  {
    float acc[64];
    #pragma unroll
    for (int n = 0; n < 64; ++n) acc[n] = 0.f;
    for (int m = 0; m < NP; ++m) {
      float xv = xb[(size_t)m * DIM + t];
      const float4* w4 = reinterpret_cast<const float4*>(wl + m * 64);
      #pragma unroll
      for (int n4 = 0; n4 < 16; ++n4) {
        float4 wv = w4[n4];
        acc[n4 * 4 + 0] = fmaf(xv, wv.x, acc[n4 * 4 + 0]);
        acc[n4 * 4 + 1] = fmaf(xv, wv.y, acc[n4 * 4 + 1]);
        acc[n4 * 4 + 2] = fmaf(xv, wv.z, acc[n4 * 4 + 2]);
        acc[n4 * 4 + 3] = fmaf(xv, wv.w, acc[n4 * 4 + 3]);
      }
    }
    #pragma unroll
    for (int n = 0; n < 64; ++n) big[n * DIM + t] = acc[n];
  }
  __syncthreads();

  // P8a: stage Wspec q-part transposed: wl[n][m] = Wspec[m][n]
  for (int i = t; i < 4096; i += THREADS) {
    int n = i >> 6, m = i & 63;
    wl[i] = Wspec[m * 192 + n];
  }
  __syncthreads();

  // P8b: W2[m][e] = sum_n wq[m][n] * ks[n][e]; overwrite own column e = t
  {
    float acc[64];
    #pragma unroll
    for (int m = 0; m < 64; ++m) acc[m] = 0.f;
    for (int n = 0; n < NP; ++n) {
      float ksv = big[n * DIM + t];
      const float4* w4 = reinterpret_cast<const float4*>(wl + n * 64);
      #pragma unroll
      for (int m4 = 0; m4 < 16; ++m4) {
        float4 wv = w4[m4];
        acc[m4 * 4 + 0] = fmaf(ksv, wv.x, acc[m4 * 4 + 0]);
        acc[m4 * 4 + 1] = fmaf(ksv, wv.y, acc[m4 * 4 + 1]);
        acc[m4 * 4 + 2] = fmaf(ksv, wv.z, acc[m4 * 4 + 2]);
        acc[m4 * 4 + 3] = fmaf(ksv, wv.w, acc[m4 * 4 + 3]);
      }
    }
    #pragma unroll
    for (int m = 0; m < 64; ++m) big[m * DIM + t] = acc[m];
  }
  __syncthreads();

  // Phase C: z rows, softmax, t accumulation.
  // z[d][e] = sum_m x[m][d] * W2[m][e]  (SCALE already folded into W2)
  // 16x8 register tile per lane; lane covers e in {lane*4+j, 256+lane*4+j}.
  // LDS reads are two contiguous-1024B ds_read_b128 per m (conflict-free).
  {
    float treg[8];
    #pragma unroll
    for (int j = 0; j < 8; ++j) treg[j] = 0.f;

    for (int iter = 0; iter < 4; ++iter) {
      const int d0 = iter * 128 + wave * 16;
      float acc[16][8];
      #pragma unroll
      for (int r = 0; r < 16; ++r)
        #pragma unroll
        for (int j = 0; j < 8; ++j) acc[r][j] = 0.f;

      #pragma unroll 2
      for (int m = 0; m < NP; ++m) {
        const float* xrow = xb + (size_t)m * DIM + d0;
        float4 xv0 = *reinterpret_cast<const float4*>(xrow);
        float4 xv1 = *reinterpret_cast<const float4*>(xrow + 4);
        float4 xv2 = *reinterpret_cast<const float4*>(xrow + 8);
        float4 xv3 = *reinterpret_cast<const float4*>(xrow + 12);
        const float* wr = big + m * DIM + lane * 4;
        float4 k0 = *reinterpret_cast<const float4*>(wr);
        float4 k1 = *reinterpret_cast<const float4*>(wr + 256);
        float xq[16] = {xv0.x, xv0.y, xv0.z, xv0.w,
                        xv1.x, xv1.y, xv1.z, xv1.w,
                        xv2.x, xv2.y, xv2.z, xv2.w,
                        xv3.x, xv3.y, xv3.z, xv3.w};
        #pragma unroll
        for (int r = 0; r < 16; ++r) {
          acc[r][0] = fmaf(xq[r], k0.x, acc[r][0]);
          acc[r][1] = fmaf(xq[r], k0.y, acc[r][1]);
          acc[r][2] = fmaf(xq[r], k0.z, acc[r][2]);
          acc[r][3] = fmaf(xq[r], k0.w, acc[r][3]);
          acc[r][4] = fmaf(xq[r], k1.x, acc[r][4]);
          acc[r][5] = fmaf(xq[r], k1.y, acc[r][5]);
          acc[r][6] = fmaf(xq[r], k1.z, acc[r][6]);
          acc[r][7] = fmaf(xq[r], k1.w, acc[r][7]);
        }
      }

      #pragma unroll
      for (int r = 0; r < 16; ++r) {
        float mx = acc[r][0];
        #pragma unroll
        for (int j = 1; j < 8; ++j) mx = fmaxf(mx, acc[r][j]);
        #pragma unroll
        for (int off = 32; off > 0; off >>= 1)
          mx = fmaxf(mx, __shfl_xor(mx, off));
        float pe[8];
        float sum = 0.f;
        #pragma unroll
        for (int j = 0; j < 8; ++j) {
          pe[j] = __expf(acc[r][j] - mx);
          sum += pe[j];
        }
        #pragma unroll
        for (int off = 32; off > 0; off >>= 1)
          sum += __shfl_xor(sum, off);
        float coef = s_l[d0 + r] / sum;
        #pragma unroll
        for (int j = 0; j < 8; ++j) treg[j] = fmaf(coef, pe[j], treg[j]);
      }
    }
    __syncthreads();  // all waves done reading W2 before reuse as partial buffer

    // store per-wave partials at big[wave][e] with the same e-mapping
    float4 t0 = {treg[0], treg[1], treg[2], treg[3]};
    float4 t1 = {treg[4], treg[5], treg[6], treg[7]};
    *reinterpret_cast<float4*>(big + wave * DIM + lane * 4) = t0;
    *reinterpret_cast<float4*>(big + wave * DIM + 256 + lane * 4) = t1;
    __syncthreads();

    float tf = 0.f;
    #pragma unroll
    for (int w = 0; w < 8; ++w) tf += big[w * DIM + t];

    float* ob = out + (size_t)b * NP * DIM + t;
    #pragma unroll 4
    for (int n = 0; n < NP; ++n) ob[n * DIM] = tf;
  }
}

extern "C" void kernel_launch(void* const* d_in, const int* in_sizes, int n_in,
                              void* d_out, int out_size, void* d_ws, size_t ws_size,
                              hipStream_t stream) {
  (void)in_sizes; (void)n_in; (void)out_size; (void)d_ws; (void)ws_size;
  const float* x     = (const float*)d_in[0];
  const float* Wq    = (const float*)d_in[1];
  const float* Wkv   = (const float*)d_in[2];
  const float* Wout  = (const float*)d_in[3];
  const float* bout  = (const float*)d_in[4];
  const float* Wspec = (const float*)d_in[5];
  float* out = (float*)d_out;

  hipFuncSetAttribute(reinterpret_cast<const void*>(center_attn_kernel),
                      hipFuncAttributeMaxDynamicSharedMemorySize, LDS_BYTES);
  center_attn_kernel<<<dim3(BATCH), dim3(THREADS), LDS_BYTES, stream>>>(
      x, Wq, Wkv, Wout, bout, Wspec, out);
}

// Round 3
// 230.966 us; speedup vs baseline: 1.4842x; 1.1855x over previous
//
#include <hip/hip_runtime.h>

#define BATCH 256
#define NP 64
#define DIM 512
#define NH 8
#define SCALE 0.125f
#define THREADS 512

typedef __attribute__((ext_vector_type(4))) float f32x4;
typedef __attribute__((ext_vector_type(8))) short bf16x8;

// LDS byte map:
//   XT   [0,65536)      bf16 xT[512 d][64 m], XOR-swizzled rows; reused as wpart f32[8][512] at the end
//   W2T  [65536,131072)  bf16 w2T[512 e][64 m] swizzled; front doubles as phase-A f32 scratch, +40960 holds wq/wk bf16
//   C    [131072,139264) bf16 C[64 m][64 mm] swizzled
//   SL   [139264,141312) f32 s[512]
//   X32  [141312,143360) f32 center row
#define XT_OFF    0
#define W2T_OFF   65536
#define C_OFF     131072
#define SL_OFF    139264
#define X32_OFF   141312
#define LDS_BYTES 143360

static __device__ __forceinline__ unsigned short f2bf(float f) {
  unsigned int u = __builtin_bit_cast(unsigned int, f);
  u += 0x7fffu + ((u >> 16) & 1u);
  return (unsigned short)(u >> 16);
}
static __device__ __forceinline__ float bf2f(unsigned short s) {
  return __builtin_bit_cast(float, ((unsigned int)s) << 16);
}

__global__ __launch_bounds__(THREADS, 2)
void center_attn_kernel(const float* __restrict__ x,
                        const float* __restrict__ Wq,
                        const float* __restrict__ Wkv,
                        const float* __restrict__ Wout,
                        const float* __restrict__ bout,
                        const float* __restrict__ Wspec,
                        float* __restrict__ out) {
  extern __shared__ char smem[];
  char* xTc  = smem + XT_OFF;
  char* w2Tc = smem + W2T_OFF;
  char* Cc   = smem + C_OFF;
  float* s_l = (float*)(smem + SL_OFF);
  float* x32 = (float*)(smem + X32_OFF);
  // phase-A f32 scratch inside the W2T region (dead before w2T is written)
  float* qc = (float*)(smem + W2T_OFF);           // 512
  float* u  = (float*)(smem + W2T_OFF + 2048);    // 4096
  float* pT = (float*)(smem + W2T_OFF + 18432);   // 512  [m][h]
  float* y  = (float*)(smem + W2T_OFF + 20480);   // 4096
  float* o  = (float*)(smem + W2T_OFF + 36864);   // 512
  unsigned short* wql = (unsigned short*)(smem + W2T_OFF + 40960); // [64][64]
  unsigned short* wkl = (unsigned short*)(smem + W2T_OFF + 49152); // [64][64]

  const int t = threadIdx.x;
  const int lane = t & 63;
  const int wave = t >> 6;
  const int b = blockIdx.x;
  const float* xb = x + (size_t)b * NP * DIM;

  // per-lane fragment byte offsets within a swizzled [rows][64]bf16 tile
  // row = base + (lane&15); k0 in {0,8,..}: byte = row*128 + ((k0*2 + (lane>>4)*16) ^ ((row&7)<<4))
  const int lo_off = ((lane & 15) * 128) + ((((lane >> 4) * 16)     ) ^ ((lane & 7) << 4));
  const int hi_off = ((lane & 15) * 128) + ((((lane >> 4) * 16) + 64) ^ ((lane & 7) << 4));

  // ---- P0: stage xT (bf16, swizzled), center row, Wspec q/k panels ----
  {
    const int d = t;
    #pragma unroll
    for (int c = 0; c < 8; ++c) {
      float v0 = xb[(c * 8 + 0) * DIM + d];
      float v1 = xb[(c * 8 + 1) * DIM + d];
      float v2 = xb[(c * 8 + 2) * DIM + d];
      float v3 = xb[(c * 8 + 3) * DIM + d];
      float v4 = xb[(c * 8 + 4) * DIM + d];
      float v5 = xb[(c * 8 + 5) * DIM + d];
      float v6 = xb[(c * 8 + 6) * DIM + d];
      float v7 = xb[(c * 8 + 7) * DIM + d];
      uint4 pk;
      pk.x = (unsigned)f2bf(v0) | ((unsigned)f2bf(v1) << 16);
      pk.y = (unsigned)f2bf(v2) | ((unsigned)f2bf(v3) << 16);
      pk.z = (unsigned)f2bf(v4) | ((unsigned)f2bf(v5) << 16);
      pk.w = (unsigned)f2bf(v6) | ((unsigned)f2bf(v7) << 16);
      *(uint4*)(xTc + d * 128 + ((c * 16) ^ ((d & 7) << 4))) = pk;
    }
    x32[t] = xb[32 * DIM + t];
    for (int i = t; i < 4096; i += THREADS) {
      int m = i >> 6, n = i & 63;
      wql[i] = f2bf(Wspec[m * 192 + n]);
      wkl[i] = f2bf(Wspec[m * 192 + 64 + n]);
    }
  }
  __syncthreads();

  // ---- P1: qc[j] = sum_d x32[d] * Wq[d][j] ----
  {
    float a0 = 0.f, a1 = 0.f, a2 = 0.f, a3 = 0.f;
    #pragma unroll 4
    for (int d = 0; d < DIM; d += 4) {
      a0 = fmaf(x32[d + 0], Wq[(size_t)(d + 0) * DIM + t], a0);
      a1 = fmaf(x32[d + 1], Wq[(size_t)(d + 1) * DIM + t], a1);
      a2 = fmaf(x32[d + 2], Wq[(size_t)(d + 2) * DIM + t], a2);
      a3 = fmaf(x32[d + 3], Wq[(size_t)(d + 3) * DIM + t], a3);
    }
    qc[t] = (a0 + a1) + (a2 + a3);
  }
  __syncthreads();

  // ---- P2: u[h][d] = sum_jj Wkv[d][h*64+jj] * qc[h*64+jj], d = t ----
  {
    const float4* wk4 = reinterpret_cast<const float4*>(Wkv + (size_t)t * 1024);
    #pragma unroll
    for (int h = 0; h < NH; ++h) {
      const float4* q4 = reinterpret_cast<const float4*>(qc + h * 64);
      float acc0 = 0.f, acc1 = 0.f;
      #pragma unroll
      for (int jj = 0; jj < 8; ++jj) {
        float4 wv = wk4[h * 16 + jj];
        float4 qv = q4[jj];
        acc0 = fmaf(wv.x, qv.x, acc0);
        acc0 = fmaf(wv.y, qv.y, acc0);
        acc0 = fmaf(wv.z, qv.z, acc0);
        acc0 = fmaf(wv.w, qv.w, acc0);
      }
      #pragma unroll
      for (int jj = 8; jj < 16; ++jj) {
        float4 wv = wk4[h * 16 + jj];
        float4 qv = q4[jj];
        acc1 = fmaf(wv.x, qv.x, acc1);
        acc1 = fmaf(wv.y, qv.y, acc1);
        acc1 = fmaf(wv.z, qv.z, acc1);
        acc1 = fmaf(wv.w, qv.w, acc1);
      }
      u[h * DIM + t] = acc0 + acc1;
    }
  }
  __syncthreads();

  // ---- P3: spatial scores + per-head softmax (wave=h, lane=m) ----
  {
    const int h = wave, m = lane;
    const float4* xr = reinterpret_cast<const float4*>(xb + (size_t)m * DIM);
    const float4* ur = reinterpret_cast<const float4*>(u + h * DIM);
    float a0 = 0.f, a1 = 0.f;
    #pragma unroll 8
    for (int i = 0; i < DIM / 4; i += 2) {
      float4 xv = xr[i], uv = ur[i];
      a0 = fmaf(xv.x, uv.x, a0);
      a0 = fmaf(xv.y, uv.y, a0);
      a0 = fmaf(xv.z, uv.z, a0);
      a0 = fmaf(xv.w, uv.w, a0);
      float4 xw = xr[i + 1], uw = ur[i + 1];
      a1 = fmaf(xw.x, uw.x, a1);
      a1 = fmaf(xw.y, uw.y, a1);
      a1 = fmaf(xw.z, uw.z, a1);
      a1 = fmaf(xw.w, uw.w, a1);
    }
    float sc = (a0 + a1) * SCALE;
    float mx = sc;
    #pragma unroll
    for (int off = 32; off > 0; off >>= 1)
      mx = fmaxf(mx, __shfl_xor(mx, off));
    float ev = __expf(sc - mx);
    float sm = ev;
    #pragma unroll
    for (int off = 32; off > 0; off >>= 1)
      sm += __shfl_xor(sm, off);
    pT[m * NH + h] = ev / sm;
  }
  __syncthreads();

  // ---- P4: y[h][d] = sum_m p[h][m] * x[m][d], d = t ----
  {
    float acc[NH];
    #pragma unroll
    for (int h = 0; h < NH; ++h) acc[h] = 0.f;
    #pragma unroll 2
    for (int m = 0; m < NP; ++m) {
      float xv = xb[(size_t)m * DIM + t];
      const float4* pp = reinterpret_cast<const float4*>(pT + m * NH);
      float4 p0 = pp[0], p1 = pp[1];
      acc[0] = fmaf(p0.x, xv, acc[0]);
      acc[1] = fmaf(p0.y, xv, acc[1]);
      acc[2] = fmaf(p0.z, xv, acc[2]);
      acc[3] = fmaf(p0.w, xv, acc[3]);
      acc[4] = fmaf(p1.x, xv, acc[4]);
      acc[5] = fmaf(p1.y, xv, acc[5]);
      acc[6] = fmaf(p1.z, xv, acc[6]);
      acc[7] = fmaf(p1.w, xv, acc[7]);
    }
    #pragma unroll
    for (int h = 0; h < NH; ++h) y[h * DIM + t] = acc[h];
  }
  __syncthreads();

  // ---- P5: o[j] = sum_d y[h][d] * Wkv[d][512+j], j = t, h = wave ----
  {
    const float* yr = y + wave * DIM;
    float a0 = 0.f, a1 = 0.f, a2 = 0.f, a3 = 0.f;
    #pragma unroll 4
    for (int d = 0; d < DIM; d += 4) {
      a0 = fmaf(yr[d + 0], Wkv[(size_t)(d + 0) * 1024 + 512 + t], a0);
      a1 = fmaf(yr[d + 1], Wkv[(size_t)(d + 1) * 1024 + 512 + t], a1);
      a2 = fmaf(yr[d + 2], Wkv[(size_t)(d + 2) * 1024 + 512 + t], a2);
      a3 = fmaf(yr[d + 3], Wkv[(size_t)(d + 3) * 1024 + 512 + t], a3);
    }
    o[t] = (a0 + a1) + (a2 + a3);
  }
  __syncthreads();

  // ---- P6: s[e] = bout[e] + sum_j o[j] * Wout[j][e], e = t ----
  {
    float a0 = bout[t], a1 = 0.f, a2 = 0.f, a3 = 0.f;
    #pragma unroll 4
    for (int j = 0; j < DIM; j += 4) {
      a0 = fmaf(o[j + 0], Wout[(size_t)(j + 0) * DIM + t], a0);
      a1 = fmaf(o[j + 1], Wout[(size_t)(j + 1) * DIM + t], a1);
      a2 = fmaf(o[j + 2], Wout[(size_t)(j + 2) * DIM + t], a2);
      a3 = fmaf(o[j + 3], Wout[(size_t)(j + 3) * DIM + t], a3);
    }
    s_l[t] = (a0 + a1) + (a2 + a3);
  }
  __syncthreads();

  // ---- C-compute: C[m][mm] = SCALE * sum_n wq[m][n]*wk[mm][n]  (batch-independent) ----
  {
    const int m = t >> 3;
    const int mm0 = (t & 7) * 8;
    float accC[8];
    #pragma unroll
    for (int j = 0; j < 8; ++j) accC[j] = 0.f;
    #pragma unroll
    for (int c8 = 0; c8 < 8; ++c8) {
      uint4 qv4 = *(const uint4*)(wql + m * 64 + c8 * 8);
      float qv[8] = {bf2f((unsigned short)(qv4.x & 0xffff)), bf2f((unsigned short)(qv4.x >> 16)),
                     bf2f((unsigned short)(qv4.y & 0xffff)), bf2f((unsigned short)(qv4.y >> 16)),
                     bf2f((unsigned short)(qv4.z & 0xffff)), bf2f((unsigned short)(qv4.z >> 16)),
                     bf2f((unsigned short)(qv4.w & 0xffff)), bf2f((unsigned short)(qv4.w >> 16))};
      #pragma unroll
      for (int j = 0; j < 8; ++j) {
        uint4 kv4 = *(const uint4*)(wkl + (mm0 + j) * 64 + c8 * 8);
        float kv[8] = {bf2f((unsigned short)(kv4.x & 0xffff)), bf2f((unsigned short)(kv4.x >> 16)),
                       bf2f((unsigned short)(kv4.y & 0xffff)), bf2f((unsigned short)(kv4.y >> 16)),
                       bf2f((unsigned short)(kv4.z & 0xffff)), bf2f((unsigned short)(kv4.z >> 16)),
                       bf2f((unsigned short)(kv4.w & 0xffff)), bf2f((unsigned short)(kv4.w >> 16))};
        float a = accC[j];
        #pragma unroll
        for (int nn = 0; nn < 8; ++nn) a = fmaf(qv[nn], kv[nn], a);
        accC[j] = a;
      }
    }
    uint4 pk;
    pk.x = (unsigned)f2bf(accC[0] * SCALE) | ((unsigned)f2bf(accC[1] * SCALE) << 16);
    pk.y = (unsigned)f2bf(accC[2] * SCALE) | ((unsigned)f2bf(accC[3] * SCALE) << 16);
    pk.z = (unsigned)f2bf(accC[4] * SCALE) | ((unsigned)f2bf(accC[5] * SCALE) << 16);
    pk.w = (unsigned)f2bf(accC[6] * SCALE) | ((unsigned)f2bf(accC[7] * SCALE) << 16);
    *(uint4*)(Cc + m * 128 + ((mm0 * 2) ^ ((m & 7) << 4))) = pk;
  }
  __syncthreads();

  // ---- W2-MFMA: W2[m][e] = sum_mm C[m][mm] * x[mm][e]; write w2T[e][m] bf16 swizzled ----
  {
    bf16x8 af0[4], af1[4];
    #pragma unroll
    for (int mt = 0; mt < 4; ++mt) {
      af0[mt] = *(const bf16x8*)(Cc + mt * 16 * 128 + lo_off);
      af1[mt] = *(const bf16x8*)(Cc + mt * 16 * 128 + hi_off);
    }
    #pragma unroll
    for (int etl = 0; etl < 4; ++etl) {
      const int e0 = (wave * 4 + etl) * 16;
      bf16x8 b0 = *(const bf16x8*)(xTc + e0 * 128 + lo_off);
      bf16x8 b1 = *(const bf16x8*)(xTc + e0 * 128 + hi_off);
      #pragma unroll
      for (int mt = 0; mt < 4; ++mt) {
        f32x4 c = {0.f, 0.f, 0.f, 0.f};
        c = __builtin_amdgcn_mfma_f32_16x16x32_bf16(af0[mt], b0, c, 0, 0, 0);
        c = __builtin_amdgcn_mfma_f32_16x16x32_bf16(af1[mt], b1, c, 0, 0, 0);
        const int e = e0 + (lane & 15);
        const int mrow = mt * 16 + (lane >> 4) * 4;
        uint2 pk;
        pk.x = (unsigned)f2bf(c[0]) | ((unsigned)f2bf(c[1]) << 16);
        pk.y = (unsigned)f2bf(c[2]) | ((unsigned)f2bf(c[3]) << 16);
        *(uint2*)(w2Tc + e * 128 + ((mrow * 2) ^ ((e & 7) << 4))) = pk;
      }
    }
  }
  __syncthreads();

  // ---- Phase C: z = xT' * W2 via MFMA, softmax (no max; |z|<<1), t accumulation ----
  float treg[32];
  #pragma unroll
  for (int et = 0; et < 32; ++et) treg[et] = 0.f;

  for (int pass = 0; pass < 4; ++pass) {
    const int d0 = pass * 128 + wave * 16;
    bf16x8 a0 = *(const bf16x8*)(xTc + d0 * 128 + lo_off);
    bf16x8 a1 = *(const bf16x8*)(xTc + d0 * 128 + hi_off);
    f32x4 acc[32];
    #pragma unroll
    for (int et = 0; et < 32; ++et) {
      bf16x8 b0 = *(const bf16x8*)(w2Tc + et * 2048 + lo_off);
      bf16x8 b1 = *(const bf16x8*)(w2Tc + et * 2048 + hi_off);
      f32x4 c = {0.f, 0.f, 0.f, 0.f};
      c = __builtin_amdgcn_mfma_f32_16x16x32_bf16(a0, b0, c, 0, 0, 0);
      c = __builtin_amdgcn_mfma_f32_16x16x32_bf16(a1, b1, c, 0, 0, 0);
      acc[et] = c;
    }
    float rs[4] = {0.f, 0.f, 0.f, 0.f};
    #pragma unroll
    for (int et = 0; et < 32; ++et) {
      #pragma unroll
      for (int r = 0; r < 4; ++r) {
        float ev = __expf(acc[et][r]);
        acc[et][r] = ev;
        rs[r] += ev;
      }
    }
    #pragma unroll
    for (int r = 0; r < 4; ++r) {
      rs[r] += __shfl_xor(rs[r], 1);
      rs[r] += __shfl_xor(rs[r], 2);
      rs[r] += __shfl_xor(rs[r], 4);
      rs[r] += __shfl_xor(rs[r], 8);
    }
    float coef[4];
    #pragma unroll
    for (int r = 0; r < 4; ++r)
      coef[r] = s_l[d0 + (lane >> 4) * 4 + r] / rs[r];
    #pragma unroll
    for (int et = 0; et < 32; ++et) {
      float tp = treg[et];
      tp = fmaf(coef[0], acc[et][0], tp);
      tp = fmaf(coef[1], acc[et][1], tp);
      tp = fmaf(coef[2], acc[et][2], tp);
      tp = fmaf(coef[3], acc[et][3], tp);
      treg[et] = tp;
    }
  }
  __syncthreads();  // done reading xT/w2T; xT region becomes wpart

  #pragma unroll
  for (int et = 0; et < 32; ++et) {
    treg[et] += __shfl_xor(treg[et], 16);
    treg[et] += __shfl_xor(treg[et], 32);
  }
  float* wpart = (float*)xTc;  // [8][512]
  if (lane < 16) {
    #pragma unroll
    for (int et = 0; et < 32; ++et)
      wpart[wave * 512 + et * 16 + lane] = treg[et];
  }
  __syncthreads();

  float tf = 0.f;
  #pragma unroll
  for (int w = 0; w < 8; ++w) tf += wpart[w * 512 + t];

  float* ob = out + (size_t)b * NP * DIM + t;
  #pragma unroll 4
  for (int n = 0; n < NP; ++n) ob[n * DIM] = tf;
}

extern "C" void kernel_launch(void* const* d_in, const int* in_sizes, int n_in,
                              void* d_out, int out_size, void* d_ws, size_t ws_size,
                              hipStream_t stream) {
  (void)in_sizes; (void)n_in; (void)out_size; (void)d_ws; (void)ws_size;
  const float* x     = (const float*)d_in[0];
  const float* Wq    = (const float*)d_in[1];
  const float* Wkv   = (const float*)d_in[2];
  const float* Wout  = (const float*)d_in[3];
  const float* bout  = (const float*)d_in[4];
  const float* Wspec = (const float*)d_in[5];
  float* out = (float*)d_out;

  hipFuncSetAttribute(reinterpret_cast<const void*>(center_attn_kernel),
                      hipFuncAttributeMaxDynamicSharedMemorySize, LDS_BYTES);
  center_attn_kernel<<<dim3(BATCH), dim3(THREADS), LDS_BYTES, stream>>>(
      x, Wq, Wkv, Wout, bout, Wspec, out);
}

// Round 4
// 199.608 us; speedup vs baseline: 1.7173x; 1.1571x over previous
//
#include <hip/hip_runtime.h>

#define BATCH 256
#define NP 64
#define DIM 512
#define NH 8
#define SCALE 0.125f
#define THREADS 512

typedef __attribute__((ext_vector_type(4))) float f32x4;
typedef __attribute__((ext_vector_type(8))) short bf16x8;

// LDS byte map:
//   XT   [0,65536)      bf16 xT[512 d][64 m], XOR-swizzled rows; reused as wpart f32[8][512] at the end
//   W2T  [65536,131072)  bf16 w2T[512 e][64 m] swizzled; front doubles as phase-A f32 scratch, +40960 holds wq/wk bf16
//   C    [131072,139264) bf16 C[64 m][64 mm] swizzled
//   SL   [139264,141312) f32 s[512]
//   X32  [141312,143360) f32 center row
#define XT_OFF    0
#define W2T_OFF   65536
#define C_OFF     131072
#define SL_OFF    139264
#define X32_OFF   141312
#define LDS_BYTES 143360

static __device__ __forceinline__ unsigned short f2bf(float f) {
  unsigned int u = __builtin_bit_cast(unsigned int, f);
  u += 0x7fffu + ((u >> 16) & 1u);
  return (unsigned short)(u >> 16);
}
static __device__ __forceinline__ float bf2f(unsigned short s) {
  return __builtin_bit_cast(float, ((unsigned int)s) << 16);
}

__global__ __launch_bounds__(THREADS, 2)
void center_attn_kernel(const float* __restrict__ x,
                        const float* __restrict__ Wq,
                        const float* __restrict__ Wkv,
                        const float* __restrict__ Wout,
                        const float* __restrict__ bout,
                        const float* __restrict__ Wspec,
                        float* __restrict__ out) {
  extern __shared__ char smem[];
  char* xTc  = smem + XT_OFF;
  char* w2Tc = smem + W2T_OFF;
  char* Cc   = smem + C_OFF;
  float* s_l = (float*)(smem + SL_OFF);
  float* x32 = (float*)(smem + X32_OFF);
  // phase-A f32 scratch inside the W2T region (dead before w2T is written)
  float* qc = (float*)(smem + W2T_OFF);           // 512
  float* u  = (float*)(smem + W2T_OFF + 2048);    // 4096  [h][d]
  float* pT = (float*)(smem + W2T_OFF + 18432);   // 512   [m][h]
  float* y  = (float*)(smem + W2T_OFF + 20480);   // 4096  [h][d]
  float* o  = (float*)(smem + W2T_OFF + 36864);   // 512
  float* scoreL = (float*)(smem + W2T_OFF + 38912); // 512 [h][m]
  unsigned short* wql = (unsigned short*)(smem + W2T_OFF + 40960); // [64][64] swz (m&7)
  unsigned short* wkl = (unsigned short*)(smem + W2T_OFF + 49152); // [64][64] swz ((m>>3)&7)

  const int t = threadIdx.x;
  const int lane = t & 63;
  const int wave = t >> 6;
  const int b = blockIdx.x;
  const float* xb = x + (size_t)b * NP * DIM;

  // per-lane fragment byte offsets within a swizzled [rows][64]bf16 tile
  const int lo_off = ((lane & 15) * 128) + ((((lane >> 4) * 16)     ) ^ ((lane & 7) << 4));
  const int hi_off = ((lane & 15) * 128) + ((((lane >> 4) * 16) + 64) ^ ((lane & 7) << 4));

  // ---- P0: stage xT (bf16, swizzled), center row, Wspec q/k panels ----
  {
    const int d = t;
    #pragma unroll
    for (int c = 0; c < 8; ++c) {
      float v0 = xb[(c * 8 + 0) * DIM + d];
      float v1 = xb[(c * 8 + 1) * DIM + d];
      float v2 = xb[(c * 8 + 2) * DIM + d];
      float v3 = xb[(c * 8 + 3) * DIM + d];
      float v4 = xb[(c * 8 + 4) * DIM + d];
      float v5 = xb[(c * 8 + 5) * DIM + d];
      float v6 = xb[(c * 8 + 6) * DIM + d];
      float v7 = xb[(c * 8 + 7) * DIM + d];
      uint4 pk;
      pk.x = (unsigned)f2bf(v0) | ((unsigned)f2bf(v1) << 16);
      pk.y = (unsigned)f2bf(v2) | ((unsigned)f2bf(v3) << 16);
      pk.z = (unsigned)f2bf(v4) | ((unsigned)f2bf(v5) << 16);
      pk.w = (unsigned)f2bf(v6) | ((unsigned)f2bf(v7) << 16);
      *(uint4*)(xTc + d * 128 + ((c * 16) ^ ((d & 7) << 4))) = pk;
    }
    x32[t] = xb[32 * DIM + t];
    // wql swizzled by (m&7); wkl swizzled by ((m>>3)&7). Lanes n consecutive -> free writes.
    for (int i = t; i < 4096; i += THREADS) {
      int m = i >> 6, n = i & 63;
      *(unsigned short*)((char*)wql + m * 128 + ((n * 2) ^ ((m & 7) << 4))) =
          f2bf(Wspec[m * 192 + n]);
      *(unsigned short*)((char*)wkl + m * 128 + ((n * 2) ^ (((m >> 3) & 7) << 4))) =
          f2bf(Wspec[m * 192 + 64 + n]);
    }
  }
  __syncthreads();

  // ---- P1: qc[j] = sum_d x32[d] * Wq[d][j] (coalesced stream) ----
  {
    float a0 = 0.f, a1 = 0.f, a2 = 0.f, a3 = 0.f;
    #pragma unroll 4
    for (int d = 0; d < DIM; d += 4) {
      a0 = fmaf(x32[d + 0], Wq[(size_t)(d + 0) * DIM + t], a0);
      a1 = fmaf(x32[d + 1], Wq[(size_t)(d + 1) * DIM + t], a1);
      a2 = fmaf(x32[d + 2], Wq[(size_t)(d + 2) * DIM + t], a2);
      a3 = fmaf(x32[d + 3], Wq[(size_t)(d + 3) * DIM + t], a3);
    }
    qc[t] = (a0 + a1) + (a2 + a3);
  }
  __syncthreads();

  // ---- P2 (coalesced rewrite): u[h][d] = sum_jj Wkv[d][h*64+jj]*qc[h*64+jj]
  //      wave owns d in [wave*64, wave*64+64); lanes cover j coalesced; 16-lane-group reduce.
  {
    const float4 qv0 = *(const float4*)(qc + 4 * lane);        // j = 4*lane
    const float4 qv1 = *(const float4*)(qc + 256 + 4 * lane);  // j = 256+4*lane
    const int h0 = lane >> 4;
    #pragma unroll 2
    for (int i = 0; i < 64; ++i) {
      const int d = wave * 64 + i;
      const float4* wr = (const float4*)(Wkv + (size_t)d * 1024);
      float4 w0 = wr[lane];
      float4 w1 = wr[64 + lane];
      float p0 = w0.x*qv0.x + w0.y*qv0.y + w0.z*qv0.z + w0.w*qv0.w;
      float p1 = w1.x*qv1.x + w1.y*qv1.y + w1.z*qv1.z + w1.w*qv1.w;
      p0 += __shfl_xor(p0, 1);  p1 += __shfl_xor(p1, 1);
      p0 += __shfl_xor(p0, 2);  p1 += __shfl_xor(p1, 2);
      p0 += __shfl_xor(p0, 4);  p1 += __shfl_xor(p1, 4);
      p0 += __shfl_xor(p0, 8);  p1 += __shfl_xor(p1, 8);
      if ((lane & 15) == 0) {
        u[h0 * 512 + d]       = p0;   // heads 0..3
        u[(4 + h0) * 512 + d] = p1;   // heads 4..7
      }
    }
  }
  __syncthreads();

  // ---- P3 (coalesced rewrite): scores[h][m] = sum_d x[m][d]*u[h][d]
  //      wave owns m in [wave*8, wave*8+8); lanes cover d coalesced; u frags hoisted.
  {
    float4 uf0[8], uf1[8];
    #pragma unroll
    for (int h = 0; h < 8; ++h) {
      uf0[h] = *(const float4*)(u + h * 512 + 4 * lane);
      uf1[h] = *(const float4*)(u + h * 512 + 256 + 4 * lane);
    }
    #pragma unroll 2
    for (int i = 0; i < 8; ++i) {
      const int m = wave * 8 + i;
      const float4* xr = (const float4*)(xb + (size_t)m * DIM);
      float4 xv0 = xr[lane];
      float4 xv1 = xr[64 + lane];
      #pragma unroll
      for (int h = 0; h < 8; ++h) {
        float p = xv0.x*uf0[h].x + xv0.y*uf0[h].y + xv0.z*uf0[h].z + xv0.w*uf0[h].w
                + xv1.x*uf1[h].x + xv1.y*uf1[h].y + xv1.z*uf1[h].z + xv1.w*uf1[h].w;
        p += __shfl_xor(p, 1);
        p += __shfl_xor(p, 2);
        p += __shfl_xor(p, 4);
        p += __shfl_xor(p, 8);
        p += __shfl_xor(p, 16);
        p += __shfl_xor(p, 32);
        if (lane == 0) scoreL[h * 64 + m] = p;
      }
    }
  }
  __syncthreads();

  // ---- P3b: per-head softmax (wave = h, lane = m) ----
  {
    float sc = scoreL[wave * 64 + lane] * SCALE;
    float mx = sc;
    #pragma unroll
    for (int off = 32; off > 0; off >>= 1)
      mx = fmaxf(mx, __shfl_xor(mx, off));
    float ev = __expf(sc - mx);
    float sm = ev;
    #pragma unroll
    for (int off = 32; off > 0; off >>= 1)
      sm += __shfl_xor(sm, off);
    pT[lane * NH + wave] = ev / sm;
  }
  __syncthreads();

  // ---- P4: y[h][d] = sum_m p[h][m] * x[m][d], d = t (coalesced) ----
  {
    float acc[NH];
    #pragma unroll
    for (int h = 0; h < NH; ++h) acc[h] = 0.f;
    #pragma unroll 2
    for (int m = 0; m < NP; ++m) {
      float xv = xb[(size_t)m * DIM + t];
      const float4* pp = reinterpret_cast<const float4*>(pT + m * NH);
      float4 p0 = pp[0], p1 = pp[1];
      acc[0] = fmaf(p0.x, xv, acc[0]);
      acc[1] = fmaf(p0.y, xv, acc[1]);
      acc[2] = fmaf(p0.z, xv, acc[2]);
      acc[3] = fmaf(p0.w, xv, acc[3]);
      acc[4] = fmaf(p1.x, xv, acc[4]);
      acc[5] = fmaf(p1.y, xv, acc[5]);
      acc[6] = fmaf(p1.z, xv, acc[6]);
      acc[7] = fmaf(p1.w, xv, acc[7]);
    }
    #pragma unroll
    for (int h = 0; h < NH; ++h) y[h * DIM + t] = acc[h];
  }
  __syncthreads();

  // ---- P5: o[j] = sum_d y[h][d] * Wkv[d][512+j], j = t, h = wave (coalesced) ----
  {
    const float* yr = y + wave * DIM;
    float a0 = 0.f, a1 = 0.f, a2 = 0.f, a3 = 0.f;
    #pragma unroll 4
    for (int d = 0; d < DIM; d += 4) {
      a0 = fmaf(yr[d + 0], Wkv[(size_t)(d + 0) * 1024 + 512 + t], a0);
      a1 = fmaf(yr[d + 1], Wkv[(size_t)(d + 1) * 1024 + 512 + t], a1);
      a2 = fmaf(yr[d + 2], Wkv[(size_t)(d + 2) * 1024 + 512 + t], a2);
      a3 = fmaf(yr[d + 3], Wkv[(size_t)(d + 3) * 1024 + 512 + t], a3);
    }
    o[t] = (a0 + a1) + (a2 + a3);
  }
  __syncthreads();

  // ---- P6: s[e] = bout[e] + sum_j o[j] * Wout[j][e], e = t (coalesced) ----
  {
    float a0 = bout[t], a1 = 0.f, a2 = 0.f, a3 = 0.f;
    #pragma unroll 4
    for (int j = 0; j < DIM; j += 4) {
      a0 = fmaf(o[j + 0], Wout[(size_t)(j + 0) * DIM + t], a0);
      a1 = fmaf(o[j + 1], Wout[(size_t)(j + 1) * DIM + t], a1);
      a2 = fmaf(o[j + 2], Wout[(size_t)(j + 2) * DIM + t], a2);
      a3 = fmaf(o[j + 3], Wout[(size_t)(j + 3) * DIM + t], a3);
    }
    s_l[t] = (a0 + a1) + (a2 + a3);
  }
  __syncthreads();

  // ---- C-compute: C[m][mm] = SCALE * sum_n wq[m][n]*wk[mm][n] (swizzled LDS reads) ----
  {
    const int m = t >> 3;
    const int mm0 = (t & 7) * 8;
    float accC[8];
    #pragma unroll
    for (int j = 0; j < 8; ++j) accC[j] = 0.f;
    #pragma unroll
    for (int c8 = 0; c8 < 8; ++c8) {
      uint4 qv4 = *(const uint4*)((char*)wql + m * 128 + ((c8 * 16) ^ ((m & 7) << 4)));
      float qv[8] = {bf2f((unsigned short)(qv4.x & 0xffff)), bf2f((unsigned short)(qv4.x >> 16)),
                     bf2f((unsigned short)(qv4.y & 0xffff)), bf2f((unsigned short)(qv4.y >> 16)),
                     bf2f((unsigned short)(qv4.z & 0xffff)), bf2f((unsigned short)(qv4.z >> 16)),
                     bf2f((unsigned short)(qv4.w & 0xffff)), bf2f((unsigned short)(qv4.w >> 16))};
      #pragma unroll
      for (int j = 0; j < 8; ++j) {
        const int mm = mm0 + j;
        uint4 kv4 = *(const uint4*)((char*)wkl + mm * 128 + ((c8 * 16) ^ (((mm >> 3) & 7) << 4)));
        float kv[8] = {bf2f((unsigned short)(kv4.x & 0xffff)), bf2f((unsigned short)(kv4.x >> 16)),
                       bf2f((unsigned short)(kv4.y & 0xffff)), bf2f((unsigned short)(kv4.y >> 16)),
                       bf2f((unsigned short)(kv4.z & 0xffff)), bf2f((unsigned short)(kv4.z >> 16)),
                       bf2f((unsigned short)(kv4.w & 0xffff)), bf2f((unsigned short)(kv4.w >> 16))};
        float a = accC[j];
        #pragma unroll
        for (int nn = 0; nn < 8; ++nn) a = fmaf(qv[nn], kv[nn], a);
        accC[j] = a;
      }
    }
    uint4 pk;
    pk.x = (unsigned)f2bf(accC[0] * SCALE) | ((unsigned)f2bf(accC[1] * SCALE) << 16);
    pk.y = (unsigned)f2bf(accC[2] * SCALE) | ((unsigned)f2bf(accC[3] * SCALE) << 16);
    pk.z = (unsigned)f2bf(accC[4] * SCALE) | ((unsigned)f2bf(accC[5] * SCALE) << 16);
    pk.w = (unsigned)f2bf(accC[6] * SCALE) | ((unsigned)f2bf(accC[7] * SCALE) << 16);
    *(uint4*)(Cc + m * 128 + ((mm0 * 2) ^ ((m & 7) << 4)));
    *(uint4*)(Cc + m * 128 + ((mm0 * 2) ^ ((m & 7) << 4))) = pk;
  }
  __syncthreads();

  // ---- W2-MFMA: W2[m][e] = sum_mm C[m][mm] * x[mm][e]; write w2T[e][m] bf16 swizzled ----
  {
    bf16x8 af0[4], af1[4];
    #pragma unroll
    for (int mt = 0; mt < 4; ++mt) {
      af0[mt] = *(const bf16x8*)(Cc + mt * 16 * 128 + lo_off);
      af1[mt] = *(const bf16x8*)(Cc + mt * 16 * 128 + hi_off);
    }
    #pragma unroll
    for (int etl = 0; etl < 4; ++etl) {
      const int e0 = (wave * 4 + etl) * 16;
      bf16x8 b0 = *(const bf16x8*)(xTc + e0 * 128 + lo_off);
      bf16x8 b1 = *(const bf16x8*)(xTc + e0 * 128 + hi_off);
      #pragma unroll
      for (int mt = 0; mt < 4; ++mt) {
        f32x4 c = {0.f, 0.f, 0.f, 0.f};
        c = __builtin_amdgcn_mfma_f32_16x16x32_bf16(af0[mt], b0, c, 0, 0, 0);
        c = __builtin_amdgcn_mfma_f32_16x16x32_bf16(af1[mt], b1, c, 0, 0, 0);
        const int e = e0 + (lane & 15);
        const int mrow = mt * 16 + (lane >> 4) * 4;
        uint2 pk;
        pk.x = (unsigned)f2bf(c[0]) | ((unsigned)f2bf(c[1]) << 16);
        pk.y = (unsigned)f2bf(c[2]) | ((unsigned)f2bf(c[3]) << 16);
        *(uint2*)(w2Tc + e * 128 + ((mrow * 2) ^ ((e & 7) << 4))) = pk;
      }
    }
  }
  __syncthreads();

  // ---- Phase C: z = xT' * W2 via MFMA, softmax (no max; |z|<<1), t accumulation ----
  float treg[32];
  #pragma unroll
  for (int et = 0; et < 32; ++et) treg[et] = 0.f;

  for (int pass = 0; pass < 4; ++pass) {
    const int d0 = pass * 128 + wave * 16;
    bf16x8 a0 = *(const bf16x8*)(xTc + d0 * 128 + lo_off);
    bf16x8 a1 = *(const bf16x8*)(xTc + d0 * 128 + hi_off);
    f32x4 acc[32];
    #pragma unroll
    for (int et = 0; et < 32; ++et) {
      bf16x8 b0 = *(const bf16x8*)(w2Tc + et * 2048 + lo_off);
      bf16x8 b1 = *(const bf16x8*)(w2Tc + et * 2048 + hi_off);
      f32x4 c = {0.f, 0.f, 0.f, 0.f};
      c = __builtin_amdgcn_mfma_f32_16x16x32_bf16(a0, b0, c, 0, 0, 0);
      c = __builtin_amdgcn_mfma_f32_16x16x32_bf16(a1, b1, c, 0, 0, 0);
      acc[et] = c;
    }
    float rs[4] = {0.f, 0.f, 0.f, 0.f};
    #pragma unroll
    for (int et = 0; et < 32; ++et) {
      #pragma unroll
      for (int r = 0; r < 4; ++r) {
        float ev = __expf(acc[et][r]);
        acc[et][r] = ev;
        rs[r] += ev;
      }
    }
    #pragma unroll
    for (int r = 0; r < 4; ++r) {
      rs[r] += __shfl_xor(rs[r], 1);
      rs[r] += __shfl_xor(rs[r], 2);
      rs[r] += __shfl_xor(rs[r], 4);
      rs[r] += __shfl_xor(rs[r], 8);
    }
    float coef[4];
    #pragma unroll
    for (int r = 0; r < 4; ++r)
      coef[r] = s_l[d0 + (lane >> 4) * 4 + r] / rs[r];
    #pragma unroll
    for (int et = 0; et < 32; ++et) {
      float tp = treg[et];
      tp = fmaf(coef[0], acc[et][0], tp);
      tp = fmaf(coef[1], acc[et][1], tp);
      tp = fmaf(coef[2], acc[et][2], tp);
      tp = fmaf(coef[3], acc[et][3], tp);
      treg[et] = tp;
    }
  }
  __syncthreads();  // done reading xT/w2T; xT region becomes wpart

  #pragma unroll
  for (int et = 0; et < 32; ++et) {
    treg[et] += __shfl_xor(treg[et], 16);
    treg[et] += __shfl_xor(treg[et], 32);
  }
  float* wpart = (float*)xTc;  // [8][512]
  if (lane < 16) {
    #pragma unroll
    for (int et = 0; et < 32; ++et)
      wpart[wave * 512 + et * 16 + lane] = treg[et];
  }
  __syncthreads();

  float tf = 0.f;
  #pragma unroll
  for (int w = 0; w < 8; ++w) tf += wpart[w * 512 + t];

  float* ob = out + (size_t)b * NP * DIM + t;
  #pragma unroll 4
  for (int n = 0; n < NP; ++n) ob[n * DIM] = tf;
}

extern "C" void kernel_launch(void* const* d_in, const int* in_sizes, int n_in,
                              void* d_out, int out_size, void* d_ws, size_t ws_size,
                              hipStream_t stream) {
  (void)in_sizes; (void)n_in; (void)out_size; (void)d_ws; (void)ws_size;
  const float* x     = (const float*)d_in[0];
  const float* Wq    = (const float*)d_in[1];
  const float* Wkv   = (const float*)d_in[2];
  const float* Wout  = (const float*)d_in[3];
  const float* bout  = (const float*)d_in[4];
  const float* Wspec = (const float*)d_in[5];
  float* out = (float*)d_out;

  hipFuncSetAttribute(reinterpret_cast<const void*>(center_attn_kernel),
                      hipFuncAttributeMaxDynamicSharedMemorySize, LDS_BYTES);
  center_attn_kernel<<<dim3(BATCH), dim3(THREADS), LDS_BYTES, stream>>>(
      x, Wq, Wkv, Wout, bout, Wspec, out);
}